// Round 1
// 328.521 us; speedup vs baseline: 1.0792x; 1.0792x over previous
//
#include <hip/hip_runtime.h>
#include <math.h>

#define NPIX 4096
#define CCH 256

typedef __attribute__((ext_vector_type(4))) float f32x4;
typedef __attribute__((ext_vector_type(8))) short s16x8;
typedef unsigned short u16;

__device__ __forceinline__ short bf16_rne(float x) {
  union { float f; unsigned u; } c; c.f = x;
  unsigned r = c.u + 0x7FFF + ((c.u >> 16) & 1);
  return (short)(r >> 16);
}
// hardware packed f32->bf16 (RNE): lo -> bits[15:0], hi -> bits[31:16]
__device__ __forceinline__ unsigned cvtpk2(float lo, float hi) {
  unsigned r;
  asm("v_cvt_pk_bf16_f32 %0, %1, %2" : "=v"(r) : "v"(lo), "v"(hi));
  return r;
}
__device__ __forceinline__ unsigned pack2(float a, float b) {
  return cvtpk2(a, b);
}

#define QSCALE 0.18033688011f   /* 0.125 * log2(e) */

// ---------------- GroupNorm stats: 32 blocks = (b, g) ----------------
__global__ __launch_bounds__(256) void gn_stats_kernel(
    const float* __restrict__ x, const float* __restrict__ gn_w, const float* __restrict__ gn_b,
    float* __restrict__ alpha, float* __restrict__ beta)
{
  const int blk = blockIdx.x;
  const int b = blk >> 3, g = blk & 7;
  const float4* base = (const float4*)(x + (size_t)(b * CCH + g * 32) * NPIX);
  double s = 0.0, ss = 0.0;
  for (int idx = threadIdx.x; idx < 32768; idx += 256) {
    float4 v = base[idx];
    s  += (double)v.x + (double)v.y + (double)v.z + (double)v.w;
    ss += (double)v.x * v.x + (double)v.y * v.y + (double)v.z * v.z + (double)v.w * v.w;
  }
  __shared__ double rs[256], rss[256];
  rs[threadIdx.x] = s; rss[threadIdx.x] = ss;
  __syncthreads();
  for (int off = 128; off > 0; off >>= 1) {
    if (threadIdx.x < off) { rs[threadIdx.x] += rs[threadIdx.x + off]; rss[threadIdx.x] += rss[threadIdx.x + off]; }
    __syncthreads();
  }
  __shared__ float smean, srstd;
  if (threadIdx.x == 0) {
    double mean = rs[0] / 131072.0;
    double var  = rss[0] / 131072.0 - mean * mean;
    smean = (float)mean;
    srstd = (float)(1.0 / sqrt(var + 1e-5));
  }
  __syncthreads();
  if (threadIdx.x < 32) {
    int c = g * 32 + threadIdx.x;
    float a = srstd * gn_w[c];
    alpha[b * CCH + c] = a;
    beta [b * CCH + c] = gn_b[c] - smean * a;
  }
}

// ---------------- Weight/bias convert: fp32 -> bf16, q rows pre-scaled ----------------
__global__ __launch_bounds__(256) void wcvt_kernel(
    const float* __restrict__ qkv_w, const float* __restrict__ proj_w, const float* __restrict__ qkv_b,
    u16* __restrict__ wq, u16* __restrict__ wp, float* __restrict__ biasq)
{
  int idx = blockIdx.x * 256 + threadIdx.x;   // 0..262143
  if (idx < 196608) {
    float v = qkv_w[idx];
    if (idx < 65536) v *= QSCALE;             // q rows (o < 256)
    wq[idx] = (u16)bf16_rne(v);
  } else {
    int j = idx - 196608;
    wp[j] = (u16)bf16_rne(proj_w[j]);
  }
  if (idx < 768) {
    float bv = qkv_b[idx];
    if (idx < 256) bv *= QSCALE;
    biasq[idx] = bv;
  }
}

// ---------------- GN apply + transpose: x[b][c][n] fp32 -> Xt[b][n][c] bf16 ----------------
__global__ __launch_bounds__(256) void gn_apply_t_kernel(
    const float* __restrict__ x, const float* __restrict__ alpha, const float* __restrict__ beta,
    u16* __restrict__ Xt)
{
  const int b = blockIdx.z, c0 = blockIdx.y * 64, n0 = blockIdx.x * 64;
  const int tid = threadIdx.x;
  __shared__ u16 T[64 * 68];
  const int n4 = (tid & 15) * 4, cr = tid >> 4;
#pragma unroll
  for (int p = 0; p < 4; ++p) {
    int cl = cr + 16 * p;
    int c = c0 + cl;
    float a = alpha[b * CCH + c], bt = beta[b * CCH + c];
    float4 v = *(const float4*)&x[((size_t)b * CCH + c) * NPIX + n0 + n4];
    T[(n4 + 0) * 68 + cl] = (u16)bf16_rne(v.x * a + bt);
    T[(n4 + 1) * 68 + cl] = (u16)bf16_rne(v.y * a + bt);
    T[(n4 + 2) * 68 + cl] = (u16)bf16_rne(v.z * a + bt);
    T[(n4 + 3) * 68 + cl] = (u16)bf16_rne(v.w * a + bt);
  }
  __syncthreads();
#pragma unroll
  for (int it = 0; it < 2; ++it) {
    int linear = it * 256 + tid;
    int n = linear >> 3, ch = linear & 7;
    s16x8 v = *(const s16x8*)&T[n * 68 + ch * 8];
    *(s16x8*)&Xt[((size_t)b * NPIX + n0 + n) * CCH + c0 + ch * 8] = v;
  }
}

// ---------------- QKV GEMM (bf16 MFMA): D[m][n] = W[m][k] Xt[n][k] + bias ----------------
// m-blocks 0..3 -> Qt[b][i][ch] (transposed store), 4..7 -> Kt, 8..11 -> V[b][c][n]
__global__ __launch_bounds__(256) void qkv_gemm_kernel(
    const u16* __restrict__ Wbf, const float* __restrict__ biasv, const u16* __restrict__ Xt,
    u16* __restrict__ Qt, u16* __restrict__ Kt, u16* __restrict__ Vb)
{
  const int nblk = blockIdx.x, m0 = blockIdx.y * 64;
  const int tid = threadIdx.x, wave = tid >> 6, lane = tid & 63;
  const int n16 = lane & 15, quad = lane >> 4;
  const int n0 = nblk * 128 + wave * 32;   // flat row (b*4096 + i)

  f32x4 acc[4][2];
#pragma unroll
  for (int a = 0; a < 4; ++a)
#pragma unroll
    for (int c = 0; c < 2; ++c) acc[a][c] = (f32x4){0.f, 0.f, 0.f, 0.f};

#pragma unroll
  for (int k0 = 0; k0 < 256; k0 += 32) {
    s16x8 af[4], bfr[2];
#pragma unroll
    for (int msub = 0; msub < 4; ++msub)
      af[msub] = *(const s16x8*)&Wbf[(size_t)(m0 + msub * 16 + n16) * 256 + k0 + quad * 8];
#pragma unroll
    for (int nsub = 0; nsub < 2; ++nsub)
      bfr[nsub] = *(const s16x8*)&Xt[(size_t)(n0 + nsub * 16 + n16) * 256 + k0 + quad * 8];
#pragma unroll
    for (int msub = 0; msub < 4; ++msub)
#pragma unroll
      for (int nsub = 0; nsub < 2; ++nsub)
        acc[msub][nsub] = __builtin_amdgcn_mfma_f32_16x16x32_bf16(af[msub], bfr[nsub], acc[msub][nsub], 0, 0, 0);
  }

  __shared__ u16 T[8704];   // qk: [n128][m 68]; v: [m64][n 136]
  if (m0 < 512) {
    // bias + pack, store transposed tile [n][m]
#pragma unroll
    for (int msub = 0; msub < 4; ++msub)
#pragma unroll
      for (int nsub = 0; nsub < 2; ++nsub) {
        float b0 = biasv[m0 + msub * 16 + quad * 4 + 0];
        float b1 = biasv[m0 + msub * 16 + quad * 4 + 1];
        float b2 = biasv[m0 + msub * 16 + quad * 4 + 2];
        float b3 = biasv[m0 + msub * 16 + quad * 4 + 3];
        uint2 w2;
        w2.x = pack2(acc[msub][nsub][0] + b0, acc[msub][nsub][1] + b1);
        w2.y = pack2(acc[msub][nsub][2] + b2, acc[msub][nsub][3] + b3);
        *(uint2*)&T[(wave * 32 + nsub * 16 + n16) * 68 + msub * 16 + quad * 4] = w2;
      }
    __syncthreads();
    u16* dst = (m0 < 256) ? Qt : Kt;
    const int coff = m0 & 255;
#pragma unroll
    for (int it = 0; it < 4; ++it) {
      int linear = it * 256 + tid;
      int n = linear >> 3, ch = linear & 7;
      s16x8 v = *(const s16x8*)&T[n * 68 + ch * 8];
      *(s16x8*)&dst[(size_t)(nblk * 128 + n) * 256 + coff + ch * 8] = v;
    }
  } else {
    // V: store [m][n] natural rows
#pragma unroll
    for (int msub = 0; msub < 4; ++msub)
#pragma unroll
      for (int nsub = 0; nsub < 2; ++nsub) {
        int ncol = wave * 32 + nsub * 16 + n16;
#pragma unroll
        for (int r = 0; r < 4; ++r) {
          int m = msub * 16 + quad * 4 + r;
          T[m * 136 + ncol] = (u16)bf16_rne(acc[msub][nsub][r] + biasv[m0 + m]);
        }
      }
    __syncthreads();
    const int b = (nblk * 128) >> 12, i0n = (nblk * 128) & 4095;
#pragma unroll
    for (int it = 0; it < 4; ++it) {
      int linear = it * 256 + tid;
      int mloc = linear >> 4, ch = linear & 15;
      s16x8 v = *(const s16x8*)&T[mloc * 136 + ch * 8];
      int c = (m0 - 512) + mloc;
      *(s16x8*)&Vb[((size_t)b * CCH + c) * NPIX + i0n + ch * 8] = v;
    }
  }
}

// ---------------- MFMA flash attention ----------------
// Block = 256 threads (4 waves); each wave owns 16 i-rows. Grid (64, 4, 4) -> 4096 waves.
// K/V staged in LDS shared by all 4 waves; P staged per-wave; defer-max rescale skip.
__global__ __launch_bounds__(256) void attn_kernel3(
    const u16* __restrict__ Qt, const u16* __restrict__ Kt,
    const u16* __restrict__ Vb, u16* __restrict__ Ot)
{
  const int b = blockIdx.z, h = blockIdx.y;
  const int tid = threadIdx.x;
  const int wave = tid >> 6, lane = tid & 63;
  const int n16 = lane & 15, quad = lane >> 4;
  const int i0w = blockIdx.x * 64 + wave * 16;

  __shared__ u16 Ks[8 * 520];
  __shared__ u16 Vs[8 * 520];
  __shared__ u16 Ps[4][2 * 512];

  const u16* Qb = Qt + (size_t)b * NPIX * 256;
  const u16* Kb = Kt + (size_t)b * NPIX * 256;
  const u16* Vg = Vb + ((size_t)b * CCH + h * 64) * NPIX;

  // Q fragments (B-op: lane holds i=n16, 8 consecutive d)
  s16x8 qf[2];
#pragma unroll
  for (int ks = 0; ks < 2; ++ks)
    qf[ks] = *(const s16x8*)&Qb[(size_t)(i0w + n16) * 256 + h * 64 + ks * 32 + quad * 8];

  f32x4 ot[4];
#pragma unroll
  for (int a = 0; a < 4; ++a) ot[a] = (f32x4){0.f, 0.f, 0.f, 0.f};
  float m_i = -1e30f;
  float l_i = 0.f;

  // staging indices: 256 threads cover 64 rows x 4 x 16ch chunks
  const int sj = tid >> 2;          // row (j for K, d for V)
  const int part = tid & 3;         // which 16-channel chunk
  const int sh = part >> 1;         // 32-channel half
  const int rr0 = (part & 1) * 2;   // first 8-ch subchunk within half
  const int sfrag = (sj >> 4) * 2 + sh;
  const int slot = sj & 15;

  for (int j0 = 0; j0 < NPIX; j0 += 64) {
    // global loads first (overlap with barrier wait)
    const s16x8* kp = (const s16x8*)&Kb[(size_t)(j0 + sj) * 256 + h * 64 + part * 16];
    const s16x8* vp = (const s16x8*)&Vg[(size_t)sj * NPIX + j0 + part * 16];
    s16x8 k0 = kp[0], k1 = kp[1];
    s16x8 v0 = vp[0], v1 = vp[1];
    __syncthreads();   // previous iter's fragment reads complete
    *(s16x8*)&Ks[sfrag * 520 + ((rr0 + 0) * 16 + slot) * 8] = k0;
    *(s16x8*)&Ks[sfrag * 520 + ((rr0 + 1) * 16 + slot) * 8] = k1;
    *(s16x8*)&Vs[sfrag * 520 + ((rr0 + 0) * 16 + slot) * 8] = v0;
    *(s16x8*)&Vs[sfrag * 520 + ((rr0 + 1) * 16 + slot) * 8] = v1;
    __syncthreads();

    // S^T = K^T Q^T  (A=K frag: m=j, B=Q frag: n=i)
    f32x4 st[4];
#pragma unroll
    for (int a = 0; a < 4; ++a) st[a] = (f32x4){0.f, 0.f, 0.f, 0.f};
#pragma unroll
    for (int ks = 0; ks < 2; ++ks)
#pragma unroll
      for (int jsub = 0; jsub < 4; ++jsub) {
        s16x8 a = *(const s16x8*)&Ks[(jsub * 2 + ks) * 520 + lane * 8];
        st[jsub] = __builtin_amdgcn_mfma_f32_16x16x32_bf16(a, qf[ks], st[jsub], 0, 0, 0);
      }

    // online softmax in log2 domain (scale folded into Wq), defer-max rescale skip
    float tm = st[0][0];
#pragma unroll
    for (int jsub = 0; jsub < 4; ++jsub)
#pragma unroll
      for (int r = 0; r < 4; ++r) tm = fmaxf(tm, st[jsub][r]);
    tm = fmaxf(tm, __shfl_xor(tm, 16));
    tm = fmaxf(tm, __shfl_xor(tm, 32));
    if (__any(tm > m_i + 8.0f)) {
      float mn = fmaxf(m_i, tm);
      float al = __builtin_amdgcn_exp2f(m_i - mn);
      m_i = mn;
      l_i *= al;
#pragma unroll
      for (int dsub = 0; dsub < 4; ++dsub)
#pragma unroll
        for (int r = 0; r < 4; ++r) ot[dsub][r] *= al;
    }
    float ps = 0.f;
#pragma unroll
    for (int jsub = 0; jsub < 4; ++jsub)
#pragma unroll
      for (int r = 0; r < 4; ++r) {
        float p = __builtin_amdgcn_exp2f(st[jsub][r] - m_i);
        st[jsub][r] = p;
        ps += p;
      }
    ps += __shfl_xor(ps, 16);
    ps += __shfl_xor(ps, 32);
    l_i += ps;

    // P -> PV B-fragment layout (wave-private LDS; no barrier needed)
#pragma unroll
    for (int jsub = 0; jsub < 4; ++jsub) {
      uint2 w2;
      w2.x = cvtpk2(st[jsub][0], st[jsub][1]);
      w2.y = cvtpk2(st[jsub][2], st[jsub][3]);
      int addr = (jsub >> 1) * 512 + (((jsub & 1) * 2 + (quad >> 1)) * 16 + n16) * 8 + (quad & 1) * 4;
      *(uint2*)&Ps[wave][addr] = w2;
    }

    // O^T += V * P
#pragma unroll
    for (int ks = 0; ks < 2; ++ks) {
      s16x8 pb = *(const s16x8*)&Ps[wave][ks * 512 + lane * 8];
#pragma unroll
      for (int dsub = 0; dsub < 4; ++dsub) {
        s16x8 a = *(const s16x8*)&Vs[(dsub * 2 + ks) * 520 + lane * 8];
        ot[dsub] = __builtin_amdgcn_mfma_f32_16x16x32_bf16(a, pb, ot[dsub], 0, 0, 0);
      }
    }
  }

  // epilogue: normalize, store O^T rows into Ot[b][i][ch] bf16
  float rl = 1.0f / l_i;
#pragma unroll
  for (int dsub = 0; dsub < 4; ++dsub) {
    uint2 w2;
    w2.x = cvtpk2(ot[dsub][0] * rl, ot[dsub][1] * rl);
    w2.y = cvtpk2(ot[dsub][2] * rl, ot[dsub][3] * rl);
    size_t addr = (size_t)((size_t)b * NPIX + i0w + n16) * 256 + h * 64 + dsub * 16 + quad * 4;
    *(uint2*)&Ot[addr] = w2;
  }
}

// ---------------- Proj GEMM (bf16 MFMA) + bias + residual, fp32 out ----------------
__global__ __launch_bounds__(256) void proj_gemm_kernel(
    const u16* __restrict__ Wp, const float* __restrict__ proj_b, const u16* __restrict__ Ot,
    const float* __restrict__ x, float* __restrict__ out)
{
  const int nblk = blockIdx.x, m0 = blockIdx.y * 64;
  const int tid = threadIdx.x, wave = tid >> 6, lane = tid & 63;
  const int n16 = lane & 15, quad = lane >> 4;
  const int n0 = nblk * 128 + wave * 32;

  f32x4 acc[4][2];
#pragma unroll
  for (int a = 0; a < 4; ++a)
#pragma unroll
    for (int c = 0; c < 2; ++c) acc[a][c] = (f32x4){0.f, 0.f, 0.f, 0.f};

#pragma unroll
  for (int k0 = 0; k0 < 256; k0 += 32) {
    s16x8 af[4], bfr[2];
#pragma unroll
    for (int msub = 0; msub < 4; ++msub)
      af[msub] = *(const s16x8*)&Wp[(size_t)(m0 + msub * 16 + n16) * 256 + k0 + quad * 8];
#pragma unroll
    for (int nsub = 0; nsub < 2; ++nsub)
      bfr[nsub] = *(const s16x8*)&Ot[(size_t)(n0 + nsub * 16 + n16) * 256 + k0 + quad * 8];
#pragma unroll
    for (int msub = 0; msub < 4; ++msub)
#pragma unroll
      for (int nsub = 0; nsub < 2; ++nsub)
        acc[msub][nsub] = __builtin_amdgcn_mfma_f32_16x16x32_bf16(af[msub], bfr[nsub], acc[msub][nsub], 0, 0, 0);
  }

  __shared__ float T[64 * 132];
#pragma unroll
  for (int msub = 0; msub < 4; ++msub)
#pragma unroll
    for (int nsub = 0; nsub < 2; ++nsub) {
      int ncol = wave * 32 + nsub * 16 + n16;
#pragma unroll
      for (int r = 0; r < 4; ++r) {
        int m = msub * 16 + quad * 4 + r;
        T[m * 132 + ncol] = acc[msub][nsub][r];
      }
    }
  __syncthreads();
  const int b = (nblk * 128) >> 12, i0n = (nblk * 128) & 4095;
#pragma unroll
  for (int it = 0; it < 8; ++it) {
    int linear = it * 256 + tid;
    int m = linear >> 5, ch = linear & 31;
    f32x4 v = *(const f32x4*)&T[m * 132 + ch * 4];
    float bs = proj_b[m0 + m];
    size_t g = ((size_t)b * CCH + m0 + m) * NPIX + i0n + ch * 4;
    float4 rv = *(const float4*)&x[g];
    float4 o;
    o.x = v[0] + bs + rv.x; o.y = v[1] + bs + rv.y;
    o.z = v[2] + bs + rv.z; o.w = v[3] + bs + rv.w;
    *(float4*)&out[g] = o;
  }
}

extern "C" void kernel_launch(void* const* d_in, const int* in_sizes, int n_in,
                              void* d_out, int out_size, void* d_ws, size_t ws_size,
                              hipStream_t stream)
{
  const float* x      = (const float*)d_in[0];
  const float* gn_w   = (const float*)d_in[1];
  const float* gn_b   = (const float*)d_in[2];
  const float* qkv_w  = (const float*)d_in[3];
  const float* qkv_b  = (const float*)d_in[4];
  const float* proj_w = (const float*)d_in[5];
  const float* proj_b = (const float*)d_in[6];
  float* out = (float*)d_out;

  float* ws    = (float*)d_ws;
  float* alpha = ws;                       // 1024
  float* beta  = ws + 1024;                // 1024
  float* biasq = ws + 2048;                // 768 (pad to 2048)
  u16*   wq    = (u16*)(ws + 4096);        // 196608 shorts = 98304 floats
  u16*   wp    = (u16*)(ws + 102400);      // 65536 shorts = 32768 floats
  u16*   Xt    = (u16*)(ws + 135168);      // 4*4096*256 shorts = 2097152 floats
  u16*   Qt    = (u16*)(ws + 2232320);
  u16*   Kt    = (u16*)(ws + 4329472);
  u16*   Vb    = (u16*)(ws + 6426624);
  u16*   Ot    = (u16*)(ws + 8523776);     // end at 10620928 floats (~42.5 MB)

  gn_stats_kernel<<<32, 256, 0, stream>>>(x, gn_w, gn_b, alpha, beta);
  wcvt_kernel<<<1024, 256, 0, stream>>>(qkv_w, proj_w, qkv_b, wq, wp, biasq);
  gn_apply_t_kernel<<<dim3(64, 4, 4), 256, 0, stream>>>(x, alpha, beta, Xt);
  qkv_gemm_kernel<<<dim3(128, 12), 256, 0, stream>>>(wq, biasq, Xt, Qt, Kt, Vb);
  attn_kernel3<<<dim3(64, 4, 4), 256, 0, stream>>>(Qt, Kt, Vb, Ot);
  proj_gemm_kernel<<<dim3(128, 4), 256, 0, stream>>>(wp, proj_b, Ot, x, out);
}

// Round 3
// 256.264 us; speedup vs baseline: 1.3835x; 1.2820x over previous
//
#include <hip/hip_runtime.h>
#include <math.h>

#define NPIX 4096
#define CCH 256

typedef __attribute__((ext_vector_type(4))) float f32x4;
typedef __attribute__((ext_vector_type(8))) short s16x8;
typedef unsigned short u16;

__device__ __forceinline__ short bf16_rne(float x) {
  union { float f; unsigned u; } c; c.f = x;
  unsigned r = c.u + 0x7FFF + ((c.u >> 16) & 1);
  return (short)(r >> 16);
}
// hardware packed f32->bf16 (RNE): lo -> bits[15:0], hi -> bits[31:16]
__device__ __forceinline__ unsigned cvtpk2(float lo, float hi) {
  unsigned r;
  asm("v_cvt_pk_bf16_f32 %0, %1, %2" : "=v"(r) : "v"(lo), "v"(hi));
  return r;
}
__device__ __forceinline__ unsigned pack2(float a, float b) {
  return cvtpk2(a, b);
}

// permlane swaps via builtins (compiler-managed hazards). Raw asm back-to-back
// VALU-write -> permlane-read has a wait-state hazard (R2 failure root cause).
__device__ __forceinline__ void plane32_swap(unsigned& a, unsigned& b) {
#if __has_builtin(__builtin_amdgcn_permlane32_swap)
  auto r = __builtin_amdgcn_permlane32_swap(a, b, false, false);
  a = r[0]; b = r[1];
#else
  asm("s_nop 2\n\tv_permlane32_swap_b32 %0, %1\n\ts_nop 2" : "+v"(a), "+v"(b));
#endif
}
__device__ __forceinline__ void plane16_swap(unsigned& a, unsigned& b) {
#if __has_builtin(__builtin_amdgcn_permlane16_swap)
  auto r = __builtin_amdgcn_permlane16_swap(a, b, false, false);
  a = r[0]; b = r[1];
#else
  asm("s_nop 2\n\tv_permlane16_swap_b32 %0, %1\n\ts_nop 2" : "+v"(a), "+v"(b));
#endif
}

// cross-quad reductions (over lanes {n16, n16+16, n16+32, n16+48}), VALU pipe only
__device__ __forceinline__ float red_max_cross(float x) {
  unsigned a = __float_as_uint(x), b = a;
  plane32_swap(a, b);
  float m = fmaxf(__uint_as_float(a), __uint_as_float(b));
  a = __float_as_uint(m); b = a;
  plane16_swap(a, b);
  return fmaxf(__uint_as_float(a), __uint_as_float(b));
}
__device__ __forceinline__ float red_sum_cross(float x) {
  unsigned a = __float_as_uint(x), b = a;
  plane32_swap(a, b);
  float m = __uint_as_float(a) + __uint_as_float(b);
  a = __float_as_uint(m); b = a;
  plane16_swap(a, b);
  return __uint_as_float(a) + __uint_as_float(b);
}

#define QSCALE 0.18033688011f   /* 0.125 * log2(e) */

// ---------------- GroupNorm partial stats: 256 blocks = (b, g, chunk) ----------------
__global__ __launch_bounds__(256) void gn_stats_part(
    const float* __restrict__ x, double2* __restrict__ partials)
{
  const int blk = blockIdx.x;
  const int bg = blk >> 3, chunk = blk & 7;
  const float4* base = (const float4*)(x + (size_t)bg * 131072 + (size_t)chunk * 16384);
  double s = 0.0, ss = 0.0;
  for (int idx = threadIdx.x; idx < 4096; idx += 256) {
    float4 v = base[idx];
    s  += (double)v.x + (double)v.y + (double)v.z + (double)v.w;
    ss += (double)v.x * v.x + (double)v.y * v.y + (double)v.z * v.z + (double)v.w * v.w;
  }
  __shared__ double rs[256], rss[256];
  rs[threadIdx.x] = s; rss[threadIdx.x] = ss;
  __syncthreads();
  for (int off = 128; off > 0; off >>= 1) {
    if (threadIdx.x < off) { rs[threadIdx.x] += rs[threadIdx.x + off]; rss[threadIdx.x] += rss[threadIdx.x + off]; }
    __syncthreads();
  }
  if (threadIdx.x == 0) {
    double2 p; p.x = rs[0]; p.y = rss[0];
    partials[blk] = p;
  }
}

// ---------------- Weight/bias convert + GN stats finalize ----------------
__global__ __launch_bounds__(256) void wcvt_kernel(
    const float* __restrict__ qkv_w, const float* __restrict__ proj_w, const float* __restrict__ qkv_b,
    const double2* __restrict__ partials, const float* __restrict__ gn_w, const float* __restrict__ gn_b,
    u16* __restrict__ wq, u16* __restrict__ wp, float* __restrict__ biasq,
    float* __restrict__ alpha, float* __restrict__ beta)
{
  int idx = blockIdx.x * 256 + threadIdx.x;   // 0..262143
  if (idx < 196608) {
    float v = qkv_w[idx];
    if (idx < 65536) v *= QSCALE;             // q rows (o < 256)
    wq[idx] = (u16)bf16_rne(v);
  } else {
    int j = idx - 196608;
    wp[j] = (u16)bf16_rne(proj_w[j]);
  }
  if (idx < 768) {
    float bv = qkv_b[idx];
    if (idx < 256) bv *= QSCALE;
    biasq[idx] = bv;
  }
  if (blockIdx.x == 0) {
    __shared__ float sm[32], sr[32];
    const int tid = threadIdx.x;
    if (tid < 32) {
      double s = 0.0, ss = 0.0;
      for (int c = 0; c < 8; ++c) { double2 p = partials[tid * 8 + c]; s += p.x; ss += p.y; }
      double mean = s / 131072.0;
      double var  = ss / 131072.0 - mean * mean;
      sm[tid] = (float)mean;
      sr[tid] = (float)(1.0 / sqrt(var + 1e-5));
    }
    __syncthreads();
#pragma unroll
    for (int p = 0; p < 4; ++p) {
      int e = p * 256 + tid;            // 0..1023 = b*256 + ch
      int ch = e & 255;
      int bg = (e >> 8) * 8 + (ch >> 5);
      float a = sr[bg] * gn_w[ch];
      alpha[e] = a;
      beta[e]  = gn_b[ch] - sm[bg] * a;
    }
  }
}

// ---------------- GN apply + transpose: x[b][c][n] fp32 -> Xt[b][n][c] bf16 ----------------
__global__ __launch_bounds__(256) void gn_apply_t_kernel(
    const float* __restrict__ x, const float* __restrict__ alpha, const float* __restrict__ beta,
    u16* __restrict__ Xt)
{
  const int b = blockIdx.z, c0 = blockIdx.y * 64, n0 = blockIdx.x * 64;
  const int tid = threadIdx.x;
  __shared__ u16 T[64 * 68];
  const int n4 = (tid & 15) * 4, cr = tid >> 4;
#pragma unroll
  for (int p = 0; p < 4; ++p) {
    int cl = cr + 16 * p;
    int c = c0 + cl;
    float a = alpha[b * CCH + c], bt = beta[b * CCH + c];
    float4 v = *(const float4*)&x[((size_t)b * CCH + c) * NPIX + n0 + n4];
    T[(n4 + 0) * 68 + cl] = (u16)bf16_rne(v.x * a + bt);
    T[(n4 + 1) * 68 + cl] = (u16)bf16_rne(v.y * a + bt);
    T[(n4 + 2) * 68 + cl] = (u16)bf16_rne(v.z * a + bt);
    T[(n4 + 3) * 68 + cl] = (u16)bf16_rne(v.w * a + bt);
  }
  __syncthreads();
#pragma unroll
  for (int it = 0; it < 2; ++it) {
    int linear = it * 256 + tid;
    int n = linear >> 3, ch = linear & 7;
    s16x8 v = *(const s16x8*)&T[n * 68 + ch * 8];
    *(s16x8*)&Xt[((size_t)b * NPIX + n0 + n) * CCH + c0 + ch * 8] = v;
  }
}

// ---------------- QKV GEMM (bf16 MFMA): D[m][n] = W[m][k] Xt[n][k] + bias ----------------
__global__ __launch_bounds__(256) void qkv_gemm_kernel(
    const u16* __restrict__ Wbf, const float* __restrict__ biasv, const u16* __restrict__ Xt,
    u16* __restrict__ Qt, u16* __restrict__ Kt, u16* __restrict__ Vb)
{
  const int nblk = blockIdx.x, m0 = blockIdx.y * 64;
  const int tid = threadIdx.x, wave = tid >> 6, lane = tid & 63;
  const int n16 = lane & 15, quad = lane >> 4;
  const int n0 = nblk * 128 + wave * 32;   // flat row (b*4096 + i)

  f32x4 acc[4][2];
#pragma unroll
  for (int a = 0; a < 4; ++a)
#pragma unroll
    for (int c = 0; c < 2; ++c) acc[a][c] = (f32x4){0.f, 0.f, 0.f, 0.f};

#pragma unroll
  for (int k0 = 0; k0 < 256; k0 += 32) {
    s16x8 af[4], bfr[2];
#pragma unroll
    for (int msub = 0; msub < 4; ++msub)
      af[msub] = *(const s16x8*)&Wbf[(size_t)(m0 + msub * 16 + n16) * 256 + k0 + quad * 8];
#pragma unroll
    for (int nsub = 0; nsub < 2; ++nsub)
      bfr[nsub] = *(const s16x8*)&Xt[(size_t)(n0 + nsub * 16 + n16) * 256 + k0 + quad * 8];
#pragma unroll
    for (int msub = 0; msub < 4; ++msub)
#pragma unroll
      for (int nsub = 0; nsub < 2; ++nsub)
        acc[msub][nsub] = __builtin_amdgcn_mfma_f32_16x16x32_bf16(af[msub], bfr[nsub], acc[msub][nsub], 0, 0, 0);
  }

  __shared__ u16 T[8704];   // qk: [n128][m 68]; v: [m64][n 136]
  if (m0 < 512) {
    // bias + pack, store transposed tile [n][m]
#pragma unroll
    for (int msub = 0; msub < 4; ++msub)
#pragma unroll
      for (int nsub = 0; nsub < 2; ++nsub) {
        float b0 = biasv[m0 + msub * 16 + quad * 4 + 0];
        float b1 = biasv[m0 + msub * 16 + quad * 4 + 1];
        float b2 = biasv[m0 + msub * 16 + quad * 4 + 2];
        float b3 = biasv[m0 + msub * 16 + quad * 4 + 3];
        uint2 w2;
        w2.x = pack2(acc[msub][nsub][0] + b0, acc[msub][nsub][1] + b1);
        w2.y = pack2(acc[msub][nsub][2] + b2, acc[msub][nsub][3] + b3);
        *(uint2*)&T[(wave * 32 + nsub * 16 + n16) * 68 + msub * 16 + quad * 4] = w2;
      }
    __syncthreads();
    u16* dst = (m0 < 256) ? Qt : Kt;
    const int coff = m0 & 255;
#pragma unroll
    for (int it = 0; it < 4; ++it) {
      int linear = it * 256 + tid;
      int n = linear >> 3, ch = linear & 7;
      s16x8 v = *(const s16x8*)&T[n * 68 + ch * 8];
      *(s16x8*)&dst[(size_t)(nblk * 128 + n) * 256 + coff + ch * 8] = v;
    }
  } else {
    // V: store [m][n] natural rows
#pragma unroll
    for (int msub = 0; msub < 4; ++msub)
#pragma unroll
      for (int nsub = 0; nsub < 2; ++nsub) {
        int ncol = wave * 32 + nsub * 16 + n16;
#pragma unroll
        for (int r = 0; r < 4; ++r) {
          int m = msub * 16 + quad * 4 + r;
          T[m * 136 + ncol] = (u16)bf16_rne(acc[msub][nsub][r] + biasv[m0 + m]);
        }
      }
    __syncthreads();
    const int b = (nblk * 128) >> 12, i0n = (nblk * 128) & 4095;
#pragma unroll
    for (int it = 0; it < 4; ++it) {
      int linear = it * 256 + tid;
      int mloc = linear >> 4, ch = linear & 15;
      s16x8 v = *(const s16x8*)&T[mloc * 136 + ch * 8];
      int c = (m0 - 512) + mloc;
      *(s16x8*)&Vb[((size_t)b * CCH + c) * NPIX + i0n + ch * 8] = v;
    }
  }
}

// ---------------- MFMA flash attention v4 ----------------
// 256 threads (4 waves), wave owns 16 i-rows. Double-buffered K/V LDS, ONE barrier
// per tile. P never touches LDS: permlane32/16_swap redistribution into PV B-frags.
__device__ __forceinline__ void kv_load(
    const u16* __restrict__ Kb, const u16* __restrict__ Vg, int h, int j0, int sj, int part,
    s16x8& k0, s16x8& k1, s16x8& v0, s16x8& v1)
{
  const s16x8* kp = (const s16x8*)&Kb[(size_t)(j0 + sj) * 256 + h * 64 + part * 16];
  const s16x8* vp = (const s16x8*)&Vg[(size_t)sj * NPIX + j0 + part * 16];
  k0 = kp[0]; k1 = kp[1]; v0 = vp[0]; v1 = vp[1];
}
__device__ __forceinline__ void kv_store(
    u16* Ksb, u16* Vsb, int sbase, int rr0,
    s16x8 k0, s16x8 k1, s16x8 v0, s16x8 v1)
{
  *(s16x8*)&Ksb[sbase + (rr0 + 0) * 128] = k0;
  *(s16x8*)&Ksb[sbase + (rr0 + 1) * 128] = k1;
  *(s16x8*)&Vsb[sbase + (rr0 + 0) * 128] = v0;
  *(s16x8*)&Vsb[sbase + (rr0 + 1) * 128] = v1;
}

__device__ __forceinline__ void attn_tile(
    const u16* Ksb, const u16* Vsb, const s16x8 qf[2], int lane,
    f32x4 ot[4], float& m_i, float& l_i)
{
  f32x4 st[4];
#pragma unroll
  for (int a = 0; a < 4; ++a) st[a] = (f32x4){0.f, 0.f, 0.f, 0.f};
  __builtin_amdgcn_s_setprio(1);
#pragma unroll
  for (int ks = 0; ks < 2; ++ks)
#pragma unroll
    for (int jsub = 0; jsub < 4; ++jsub) {
      s16x8 a = *(const s16x8*)&Ksb[(jsub * 2 + ks) * 520 + lane * 8];
      st[jsub] = __builtin_amdgcn_mfma_f32_16x16x32_bf16(a, qf[ks], st[jsub], 0, 0, 0);
    }
  __builtin_amdgcn_s_setprio(0);

  // row max: depth-4 tree + permlane cross-quad reduce (no LDS)
  float t0 = fmaxf(fmaxf(st[0][0], st[0][1]), fmaxf(st[0][2], st[0][3]));
  float t1 = fmaxf(fmaxf(st[1][0], st[1][1]), fmaxf(st[1][2], st[1][3]));
  float t2 = fmaxf(fmaxf(st[2][0], st[2][1]), fmaxf(st[2][2], st[2][3]));
  float t3 = fmaxf(fmaxf(st[3][0], st[3][1]), fmaxf(st[3][2], st[3][3]));
  float tm = fmaxf(fmaxf(t0, t1), fmaxf(t2, t3));
  tm = red_max_cross(tm);

  // defer-max: only rescale when max grew by >8 (log2 domain)
  if (__any(tm > m_i + 8.0f)) {
    float mn = fmaxf(m_i, tm);
    float al = __builtin_amdgcn_exp2f(m_i - mn);
    m_i = mn;
    l_i *= al;
#pragma unroll
    for (int dsub = 0; dsub < 4; ++dsub)
#pragma unroll
      for (int r = 0; r < 4; ++r) ot[dsub][r] *= al;
  }

#pragma unroll
  for (int jsub = 0; jsub < 4; ++jsub)
#pragma unroll
    for (int r = 0; r < 4; ++r)
      st[jsub][r] = __builtin_amdgcn_exp2f(st[jsub][r] - m_i);

  float s0 = (st[0][0] + st[0][1]) + (st[0][2] + st[0][3]);
  float s1 = (st[1][0] + st[1][1]) + (st[1][2] + st[1][3]);
  float s2 = (st[2][0] + st[2][1]) + (st[2][2] + st[2][3]);
  float s3 = (st[3][0] + st[3][1]) + (st[3][2] + st[3][3]);
  float ps = (s0 + s1) + (s2 + s3);
  ps = red_sum_cross(ps);
  l_i += ps;

  // P (C-frag, rows j) -> PV B-frags: pack pairs then permlane32+16 swap.
  // After swaps: a0 = [A0@q0, A0@q2, B0@q0, B0@q2] per dest quad (word0),
  //              b0 = [A0@q1, A0@q3, B0@q1, B0@q3] (word2); a1/b1 words 1/3.
  s16x8 pb[2];
#pragma unroll
  for (int ks = 0; ks < 2; ++ks) {
    unsigned a0 = cvtpk2(st[2 * ks][0], st[2 * ks][1]);
    unsigned a1 = cvtpk2(st[2 * ks][2], st[2 * ks][3]);
    unsigned b0 = cvtpk2(st[2 * ks + 1][0], st[2 * ks + 1][1]);
    unsigned b1 = cvtpk2(st[2 * ks + 1][2], st[2 * ks + 1][3]);
    plane32_swap(a0, b0);
    plane16_swap(a0, b0);
    plane32_swap(a1, b1);
    plane16_swap(a1, b1);
    union { unsigned u[4]; s16x8 v; } pu;
    pu.u[0] = a0; pu.u[1] = a1; pu.u[2] = b0; pu.u[3] = b1;
    pb[ks] = pu.v;
  }

  // O^T += V * P
  __builtin_amdgcn_s_setprio(1);
#pragma unroll
  for (int ks = 0; ks < 2; ++ks)
#pragma unroll
    for (int dsub = 0; dsub < 4; ++dsub) {
      s16x8 a = *(const s16x8*)&Vsb[(dsub * 2 + ks) * 520 + lane * 8];
      ot[dsub] = __builtin_amdgcn_mfma_f32_16x16x32_bf16(a, pb[ks], ot[dsub], 0, 0, 0);
    }
  __builtin_amdgcn_s_setprio(0);
}

__global__ __launch_bounds__(256, 4) void attn_kernel4(
    const u16* __restrict__ Qt, const u16* __restrict__ Kt,
    const u16* __restrict__ Vb, u16* __restrict__ Ot)
{
  const int b = blockIdx.z, h = blockIdx.y;
  const int tid = threadIdx.x;
  const int wave = tid >> 6, lane = tid & 63;
  const int n16 = lane & 15, quad = lane >> 4;
  const int i0w = blockIdx.x * 64 + wave * 16;

  __shared__ u16 Ks[2][8 * 520];
  __shared__ u16 Vs[2][8 * 520];

  const u16* Qb = Qt + (size_t)b * NPIX * 256;
  const u16* Kb = Kt + (size_t)b * NPIX * 256;
  const u16* Vg = Vb + ((size_t)b * CCH + h * 64) * NPIX;

  // Q fragments (B-op: lane holds i=n16, 8 consecutive d)
  s16x8 qf[2];
#pragma unroll
  for (int ks = 0; ks < 2; ++ks)
    qf[ks] = *(const s16x8*)&Qb[(size_t)(i0w + n16) * 256 + h * 64 + ks * 32 + quad * 8];

  f32x4 ot[4];
#pragma unroll
  for (int a = 0; a < 4; ++a) ot[a] = (f32x4){0.f, 0.f, 0.f, 0.f};
  float m_i = -1e30f;
  float l_i = 0.f;

  // staging indices: 256 threads cover 64 rows x 4 x 16ch chunks
  const int sj = tid >> 2;          // row (j for K, d for V)
  const int part = tid & 3;         // which 16-channel chunk
  const int sh = part >> 1;
  const int rr0 = (part & 1) * 2;
  const int sbase = ((sj >> 4) * 2 + sh) * 520 + (sj & 15) * 8;

  s16x8 k0, k1, v0, v1;

  // prologue: tile 0
  kv_load(Kb, Vg, h, 0, sj, part, k0, k1, v0, v1);
  kv_store(Ks[0], Vs[0], sbase, rr0, k0, k1, v0, v1);
  __syncthreads();

#pragma unroll 1
  for (int t = 0; t < 62; t += 2) {
    kv_load(Kb, Vg, h, (t + 1) * 64, sj, part, k0, k1, v0, v1);
    attn_tile(Ks[0], Vs[0], qf, lane, ot, m_i, l_i);
    kv_store(Ks[1], Vs[1], sbase, rr0, k0, k1, v0, v1);
    __syncthreads();
    kv_load(Kb, Vg, h, (t + 2) * 64, sj, part, k0, k1, v0, v1);
    attn_tile(Ks[1], Vs[1], qf, lane, ot, m_i, l_i);
    kv_store(Ks[0], Vs[0], sbase, rr0, k0, k1, v0, v1);
    __syncthreads();
  }
  // tiles 62, 63
  kv_load(Kb, Vg, h, 63 * 64, sj, part, k0, k1, v0, v1);
  attn_tile(Ks[0], Vs[0], qf, lane, ot, m_i, l_i);
  kv_store(Ks[1], Vs[1], sbase, rr0, k0, k1, v0, v1);
  __syncthreads();
  attn_tile(Ks[1], Vs[1], qf, lane, ot, m_i, l_i);

  // epilogue: normalize, store O^T rows into Ot[b][i][ch] bf16
  float rl = 1.0f / l_i;
#pragma unroll
  for (int dsub = 0; dsub < 4; ++dsub) {
    uint2 w2;
    w2.x = cvtpk2(ot[dsub][0] * rl, ot[dsub][1] * rl);
    w2.y = cvtpk2(ot[dsub][2] * rl, ot[dsub][3] * rl);
    size_t addr = (size_t)((size_t)b * NPIX + i0w + n16) * 256 + h * 64 + dsub * 16 + quad * 4;
    *(uint2*)&Ot[addr] = w2;
  }
}

// ---------------- Proj GEMM (bf16 MFMA) + bias + residual, fp32 out ----------------
__global__ __launch_bounds__(256) void proj_gemm_kernel(
    const u16* __restrict__ Wp, const float* __restrict__ proj_b, const u16* __restrict__ Ot,
    const float* __restrict__ x, float* __restrict__ out)
{
  const int nblk = blockIdx.x, m0 = blockIdx.y * 64;
  const int tid = threadIdx.x, wave = tid >> 6, lane = tid & 63;
  const int n16 = lane & 15, quad = lane >> 4;
  const int n0 = nblk * 128 + wave * 32;

  f32x4 acc[4][2];
#pragma unroll
  for (int a = 0; a < 4; ++a)
#pragma unroll
    for (int c = 0; c < 2; ++c) acc[a][c] = (f32x4){0.f, 0.f, 0.f, 0.f};

#pragma unroll
  for (int k0 = 0; k0 < 256; k0 += 32) {
    s16x8 af[4], bfr[2];
#pragma unroll
    for (int msub = 0; msub < 4; ++msub)
      af[msub] = *(const s16x8*)&Wp[(size_t)(m0 + msub * 16 + n16) * 256 + k0 + quad * 8];
#pragma unroll
    for (int nsub = 0; nsub < 2; ++nsub)
      bfr[nsub] = *(const s16x8*)&Ot[(size_t)(n0 + nsub * 16 + n16) * 256 + k0 + quad * 8];
#pragma unroll
    for (int msub = 0; msub < 4; ++msub)
#pragma unroll
      for (int nsub = 0; nsub < 2; ++nsub)
        acc[msub][nsub] = __builtin_amdgcn_mfma_f32_16x16x32_bf16(af[msub], bfr[nsub], acc[msub][nsub], 0, 0, 0);
  }

  __shared__ float T[64 * 132];
#pragma unroll
  for (int msub = 0; msub < 4; ++msub)
#pragma unroll
    for (int nsub = 0; nsub < 2; ++nsub) {
      int ncol = wave * 32 + nsub * 16 + n16;
#pragma unroll
      for (int r = 0; r < 4; ++r) {
        int m = msub * 16 + quad * 4 + r;
        T[m * 132 + ncol] = acc[msub][nsub][r];
      }
    }
  __syncthreads();
  const int b = (nblk * 128) >> 12, i0n = (nblk * 128) & 4095;
#pragma unroll
  for (int it = 0; it < 8; ++it) {
    int linear = it * 256 + tid;
    int m = linear >> 5, ch = linear & 31;
    f32x4 v = *(const f32x4*)&T[m * 132 + ch * 4];
    float bs = proj_b[m0 + m];
    size_t g = ((size_t)b * CCH + m0 + m) * NPIX + i0n + ch * 4;
    float4 rv = *(const float4*)&x[g];
    float4 o;
    o.x = v[0] + bs + rv.x; o.y = v[1] + bs + rv.y;
    o.z = v[2] + bs + rv.z; o.w = v[3] + bs + rv.w;
    *(float4*)&out[g] = o;
  }
}

extern "C" void kernel_launch(void* const* d_in, const int* in_sizes, int n_in,
                              void* d_out, int out_size, void* d_ws, size_t ws_size,
                              hipStream_t stream)
{
  const float* x      = (const float*)d_in[0];
  const float* gn_w   = (const float*)d_in[1];
  const float* gn_b   = (const float*)d_in[2];
  const float* qkv_w  = (const float*)d_in[3];
  const float* qkv_b  = (const float*)d_in[4];
  const float* proj_w = (const float*)d_in[5];
  const float* proj_b = (const float*)d_in[6];
  float* out = (float*)d_out;

  float* ws    = (float*)d_ws;
  float* alpha = ws;                       // 1024
  float* beta  = ws + 1024;                // 1024
  float* biasq = ws + 2048;                // 768
  double2* partials = (double2*)(ws + 2816); // 256 double2 = 1024 floats -> ends 3840
  u16*   wq    = (u16*)(ws + 4096);        // 196608 shorts = 98304 floats
  u16*   wp    = (u16*)(ws + 102400);      // 65536 shorts = 32768 floats
  u16*   Xt    = (u16*)(ws + 135168);      // 4*4096*256 shorts = 2097152 floats
  u16*   Qt    = (u16*)(ws + 2232320);
  u16*   Kt    = (u16*)(ws + 4329472);
  u16*   Vb    = (u16*)(ws + 6426624);
  u16*   Ot    = (u16*)(ws + 8523776);     // end at 10620928 floats (~42.5 MB)

  gn_stats_part<<<256, 256, 0, stream>>>(x, partials);
  wcvt_kernel<<<1024, 256, 0, stream>>>(qkv_w, proj_w, qkv_b, partials, gn_w, gn_b,
                                        wq, wp, biasq, alpha, beta);
  gn_apply_t_kernel<<<dim3(64, 4, 4), 256, 0, stream>>>(x, alpha, beta, Xt);
  qkv_gemm_kernel<<<dim3(128, 12), 256, 0, stream>>>(wq, biasq, Xt, Qt, Kt, Vb);
  attn_kernel4<<<dim3(64, 4, 4), 256, 0, stream>>>(Qt, Kt, Vb, Ot);
  proj_gemm_kernel<<<dim3(128, 4), 256, 0, stream>>>(wp, proj_b, Ot, x, out);
}